// Round 15
// baseline (215.075 us; speedup 1.0000x reference)
//
#include <hip/hip_runtime.h>
#include <hip/hip_bf16.h>

typedef unsigned short u16;
typedef unsigned int u32;
typedef short bf16x8 __attribute__((ext_vector_type(8)));
typedef _Float16 f16x8 __attribute__((ext_vector_type(8)));
typedef float f32x4 __attribute__((ext_vector_type(4)));

__device__ __forceinline__ u16 f2bf(float f) {
    u32 u = __builtin_bit_cast(u32, f);
    u32 r = (u + 0x7FFFu + ((u >> 16) & 1u)) >> 16;
    return (u16)r;
}
__device__ __forceinline__ u16 f2h(float f) {
    _Float16 h = (_Float16)f;
    return __builtin_bit_cast(u16, h);
}
__device__ __forceinline__ float h2f(u16 u) {
    return (float)__builtin_bit_cast(_Float16, u);
}

// async global->LDS, 16B per lane (lds dest = wave-uniform base + lane*16)
__device__ __forceinline__ void lds16(const void* g, void* s) {
    __builtin_amdgcn_global_load_lds(
        (const __attribute__((address_space(1))) u32*)g,
        (__attribute__((address_space(3))) u32*)s, 16, 0, 0);
}

// ---------------- PRE (fused): blocks [0,4096): Wl transpose -> f16/bf16;
//                  blocks [4096, 4096+M/4): path + x convert ------------------------
__global__ __launch_bounds__(256) void pre_kernel(
    const float* __restrict__ x, const float* __restrict__ Wd,
    const float* __restrict__ bd, const float* __restrict__ Wl,
    float* __restrict__ path, u16* __restrict__ xb, u16* __restrict__ wlt,
    int as_f16, int M) {
    __shared__ float tile[64][65];
    const int bid = blockIdx.x;

    if (bid < 4096) {  // ---- Wl (l,h,n) fp32 -> WlT (l,n,h) ----
        int nb = bid & 15, hb = (bid >> 4) & 15, l = bid >> 8;
        int t = threadIdx.x;
        int r = t >> 2, cq = (t & 3) << 4;

        const float* src = Wl + ((size_t)(l * 1024 + hb * 64 + r)) * 1024 + nb * 64 + cq;
#pragma unroll
        for (int j = 0; j < 4; ++j) {
            float4 w = ((const float4*)src)[j];
            tile[r][cq + 4 * j + 0] = w.x;
            tile[r][cq + 4 * j + 1] = w.y;
            tile[r][cq + 4 * j + 2] = w.z;
            tile[r][cq + 4 * j + 3] = w.w;
        }
        __syncthreads();
        union { u16 u[16]; uint4 q[2]; } pk;
#pragma unroll
        for (int j = 0; j < 16; ++j)
            pk.u[j] = as_f16 ? f2h(tile[cq + j][r]) : f2bf(tile[cq + j][r]);
        u16* dst = wlt + ((size_t)(l * 1024 + nb * 64 + r)) * 1024 + hb * 64 + cq;
        ((uint4*)dst)[0] = pk.q[0];
        ((uint4*)dst)[1] = pk.q[1];
        return;
    }

    // ---- path + x convert ----
    int lane = threadIdx.x & 63;
    int wid = threadIdx.x >> 6;
    int m = (bid - 4096) * 4 + wid;
    if (m >= M) return;

    const float* xr = x + (size_t)m * 1024;
    float v[16];
#pragma unroll
    for (int i = 0; i < 16; ++i) v[i] = xr[lane + 64 * i];
#pragma unroll
    for (int i = 0; i < 16; ++i)
        xb[(size_t)m * 1024 + lane + 64 * i] = as_f16 ? f2h(v[i]) : f2bf(v[i]);

    int leaf = lane & 15;
    int nd[4], bit[4];
#pragma unroll
    for (int k = 0; k < 4; ++k) {
        nd[k] = (1 << k) - 1 + (leaf & ((1 << k) - 1));
        bit[k] = (leaf >> k) & 1;
    }
    float z[4] = {0.f, 0.f, 0.f, 0.f};

    const float2* Wd2 = (const float2*)Wd;  // [n][h] -> (k0,k1)
    for (int n = 0; n < 15; ++n) {
        float s0 = 0.f, s1 = 0.f;
#pragma unroll
        for (int i = 0; i < 16; ++i) {
            float2 w = Wd2[n * 1024 + lane + 64 * i];
            s0 += v[i] * w.x;
            s1 += v[i] * w.y;
        }
#pragma unroll
        for (int off = 32; off; off >>= 1) {
            s0 += __shfl_xor(s0, off, 64);
            s1 += __shfl_xor(s1, off, 64);
        }
#pragma unroll
        for (int k = 0; k < 4; ++k)
            if (nd[k] == n) z[k] = bit[k] ? s1 : s0;
    }
    float p = 1.f;
#pragma unroll
    for (int k = 0; k < 4; ++k) {
        float zz = z[k] + bd[nd[k] * 2 + bit[k]];
        p *= 1.f / (1.f + expf(-zz));
    }
    if (lane < 16) path[(size_t)m * 16 + leaf] = p;
}

// ---------------- G16: 256x256, ks-major, r13 schedule, but 16 waves x 64x64 tiles.
// acc=64 regs + transient 32 -> ~116 unified/wave -> 4 waves/SIMD: waves slipping
// around the per-tile barrier overlap LDS reads with MFMAs across waves. ------------
__global__ __launch_bounds__(1024, 4) void tree_gemm8(
    const u16* __restrict__ xh, const u16* __restrict__ wlt,
    const float* __restrict__ path, float* __restrict__ out,
    u16* __restrict__ part16, int M) {
    __shared__ __align__(16) u16 Asm[2][2][128 * 64];  // [ks-parity][m-half]
    __shared__ __align__(16) u16 Bsm[2][2][128 * 64];  // [t-parity][n-half]
    __shared__ u16 psm_h[4][256];                      // f16 path [leaf][row]

    const int tid = threadIdx.x, lane = tid & 63, w = tid >> 6;  // w in [0,16)
    const int wm = w >> 2, wn = w & 3;  // 4x4 waves, wave tile 64x64
    // XCD quad-swizzle: 4 n0-blocks sharing an A panel + same z -> one XCD
    const int nbm = M >> 8;
    int xb_, yb_, zb_;
    {
        int bid = blockIdx.x;
        if ((nbm << 4) == 256) {
            int k = bid & 7, s = bid >> 3;
            zb_ = k >> 1; yb_ = (k & 1) * 8 + (s >> 2); xb_ = s & 3;
        } else {
            xb_ = bid & 3; int t2 = bid >> 2; yb_ = t2 % nbm; zb_ = t2 / nbm;
        }
    }
    const int n0 = xb_ * 256, m0 = yb_ * 256, z = zb_;
    const int z4 = z * 4;
    const int rl = lane >> 3;                      // dest row & 7 within 8-row seg
    const int srcswz = ((lane & 7) ^ rl) << 4;     // pre-swizzled source col
    const int frow = lane & 15;                    // frag row (16-row frags)
    const int coff0 = ((lane >> 4) << 4) ^ ((lane & 7) << 4);

    // stage f16 path columns for this z-group: psm_h[lz][row] (1024 thr: one pass)
    {
        int r = tid >> 2, lz = tid & 3;
        psm_h[lz][r] = f2h(path[(size_t)(m0 + r) * 16 + z4 + lz]);
    }

#define ISSUE_A(dst_, ks_)                                                          \
    {                                                                               \
        _Pragma("unroll") for (int h_ = 0; h_ < 2; ++h_)                            \
            lds16((const char*)xh +                                                 \
                      (size_t)(m0 + h_ * 128 + w * 8 + rl) * 2048 +                 \
                      ((ks_) << 7) + srcswz,                                        \
                  (dst_) + h_ * 16384 + w * 1024);                                  \
    }
#define ISSUE_B(dst_, t_)                                                           \
    if ((t_) < 64) {                                                                \
        size_t lb_ = (size_t)(z4 + ((t_) & 3)) * 2097152 +                          \
                     ((size_t)((t_) >> 2) << 7);                                    \
        _Pragma("unroll") for (int h_ = 0; h_ < 2; ++h_)                            \
            lds16((const char*)wlt + lb_ +                                          \
                      (size_t)(n0 + h_ * 128 + w * 8 + rl) * 2048 + srcswz,         \
                  (dst_) + h_ * 16384 + w * 1024);                                  \
    }
#define LDA4(aB_, co_)                                                              \
    _Pragma("unroll") for (int q_ = 0; q_ < 4; ++q_)                                \
        aR[q_] = *(const f16x8*)((aB_) + q_ * 2048 + (co_));
#define LDB4(bB_, co_)                                                              \
    _Pragma("unroll") for (int q_ = 0; q_ < 4; ++q_)                                \
        bR[q_] = *(const f16x8*)((bB_) + q_ * 2048 + (co_));
#define LDP(ll)                                                                     \
    _Pragma("unroll") for (int q_ = 0; q_ < 4; ++q_)                                \
        p2[q_] = __builtin_bit_cast(                                                \
            _Float16, psm_h[ll][wm * 64 + q_ * 16 + frow]);
#define SCALE                                                                       \
    _Pragma("unroll") for (int q_ = 0; q_ < 4; ++q_) aR[q_] *= p2[q_];
#define MM16                                                                        \
    _Pragma("unroll") for (int mq_ = 0; mq_ < 4; ++mq_)                             \
    _Pragma("unroll") for (int nq_ = 0; nq_ < 4; ++nq_)                             \
        acc[mq_][nq_] = __builtin_amdgcn_mfma_f32_16x16x32_f16(                     \
            aR[mq_], bR[nq_], acc[mq_][nq_], 0, 0, 0);
#define BAR __builtin_amdgcn_s_barrier()
#define SCHED0 __builtin_amdgcn_sched_barrier(0)
#define PRIO1 __builtin_amdgcn_s_setprio(1)
#define PRIO0 __builtin_amdgcn_s_setprio(0)
#define VM0 asm volatile("s_waitcnt vmcnt(0)" ::: "memory")
#define VM2 asm volatile("s_waitcnt vmcnt(2)" ::: "memory")
#define NOPX ((void)0)

// one leaf-tile, ONE barrier (at end); two kf half-steps; transient regs die per kf.
#define TILE(aB_, bB_, ll, EB, EA, WT)                                              \
    {                                                                               \
        _Float16 p2[4];                                                             \
        LDP(ll);                                                                    \
        {                                                                           \
            f16x8 aR[4], bR[4];                                                     \
            LDA4(aB_, coff0); LDB4(bB_, coff0);                                     \
            EB; EA;                                                                 \
            SCALE;                                                                  \
            PRIO1; MM16; PRIO0;                                                     \
        }                                                                           \
        {                                                                           \
            f16x8 aR[4], bR[4];                                                     \
            LDA4(aB_, coff0 ^ 64); LDB4(bB_, coff0 ^ 64);                           \
            SCALE;                                                                  \
            PRIO1; MM16; PRIO0;                                                     \
        }                                                                           \
        WT; BAR;                                                                    \
    }

    f32x4 acc[4][4];
#pragma unroll
    for (int a = 0; a < 4; ++a)
#pragma unroll
        for (int b = 0; b < 4; ++b) acc[a][b] = (f32x4){0.f, 0.f, 0.f, 0.f};

    const char* aBase0 = (const char*)Asm[0][wm >> 1] + ((wm & 1) * 64 + frow) * 128;
    const char* aBase1 = (const char*)Asm[1][wm >> 1] + ((wm & 1) * 64 + frow) * 128;
    const char* bBase0 = (const char*)Bsm[0][wn >> 1] + ((wn & 1) * 64 + frow) * 128;
    const char* bBase1 = (const char*)Bsm[1][wn >> 1] + ((wn & 1) * 64 + frow) * 128;
    char* aSlot0 = (char*)Asm[0][0];
    char* aSlot1 = (char*)Asm[1][0];
    char* bSlot0 = (char*)Bsm[0][0];
    char* bSlot1 = (char*)Bsm[1][0];

    // prologue: A(ks0) + B(0); drain fully (incl. psm ds_writes); sync
    ISSUE_A(aSlot0, 0);
    ISSUE_B(bSlot0, 0);
    asm volatile("s_waitcnt vmcnt(0) lgkmcnt(0)" ::: "memory");
    BAR;
    SCHED0;

    // ledger per tile (2-load units), issues B then A:
    // ll0: issue B(t+1) -> [B2]             -> VM0
    // ll1: issue B(t+2), A(ks+1) -> [B2,A2] -> VM2 (drain B, keep A flying)
    // ll2: entry [A2], issue B -> [A2,B2]   -> VM0
    // ll3: issue B -> [B2]                  -> VM0
#pragma unroll 1
    for (int ks = 0; ks < 15; ++ks) {
        const int t4 = ks << 2;
        const char* aB = (ks & 1) ? aBase1 : aBase0;
        char* aD = (ks & 1) ? aSlot0 : aSlot1;  // slot for A(ks+1)
        TILE(aB, bBase0, 0, ISSUE_B(bSlot1, t4 + 1), NOPX, VM0);
        TILE(aB, bBase1, 1, ISSUE_B(bSlot0, t4 + 2), ISSUE_A(aD, ks + 1), VM2);
        TILE(aB, bBase0, 2, ISSUE_B(bSlot1, t4 + 3), NOPX, VM0);
        TILE(aB, bBase1, 3, ISSUE_B(bSlot0, t4 + 4), NOPX, VM0);
    }
    {   // ks = 15 tail: no A prefetch; B issues run out at t=63
        const char* aB = aBase1;
        TILE(aB, bBase0, 0, ISSUE_B(bSlot1, 61), NOPX, VM0);
        TILE(aB, bBase1, 1, ISSUE_B(bSlot0, 62), NOPX, VM0);
        TILE(aB, bBase0, 2, ISSUE_B(bSlot1, 63), NOPX, VM0);
        TILE(aB, bBase1, 3, NOPX, NOPX, NOPX);
    }

    // epilogue: z=0 -> f32 to out; z>0 -> f16 partial (z-1)
    const int r0 = m0 + wm * 64 + ((lane >> 4) << 2);
    const int c0 = n0 + wn * 64 + frow;
    if (z == 0) {
#pragma unroll
        for (int mf = 0; mf < 4; ++mf)
#pragma unroll
            for (int jj = 0; jj < 4; ++jj)
#pragma unroll
                for (int nf = 0; nf < 4; ++nf)
                    out[(size_t)(r0 + mf * 16 + jj) * 1024 + c0 + nf * 16] =
                        acc[mf][nf][jj];
    } else {
        u16* po = part16 + (size_t)(z - 1) * M * 1024;
#pragma unroll
        for (int mf = 0; mf < 4; ++mf)
#pragma unroll
            for (int jj = 0; jj < 4; ++jj)
#pragma unroll
                for (int nf = 0; nf < 4; ++nf)
                    po[(size_t)(r0 + mf * 16 + jj) * 1024 + c0 + nf * 16] =
                        f2h(acc[mf][nf][jj]);
    }
#undef ISSUE_A
#undef ISSUE_B
#undef LDA4
#undef LDB4
#undef LDP
#undef SCALE
#undef MM16
#undef BAR
#undef SCHED0
#undef PRIO1
#undef PRIO0
#undef VM0
#undef VM2
#undef NOPX
#undef TILE
}

// ---------------- FB: round-2 dual-accumulator bf16 GEMM (fallback) -------
__global__ __launch_bounds__(256) void tree_gemm_fb(
    const u16* __restrict__ xb, const u16* __restrict__ wlt,
    const float* __restrict__ path, float* __restrict__ pout,
    int M, int LPB, int lgLPB) {
    __shared__ __align__(16) u16 Asm[128 * 64];
    __shared__ __align__(16) u16 Bsm[128 * 64];
    __shared__ float psm[128][16];

    const int tid = threadIdx.x, lane = tid & 63, wid = tid >> 6;
    const int wm = wid >> 1, wn = wid & 1;
    const int m0 = blockIdx.y * 128, n0 = blockIdx.x * 128;
    const int lbase = blockIdx.z * LPB;

    for (int i = tid; i < (128 << lgLPB); i += 256) {
        int r = i >> lgLPB, c = i & (LPB - 1);
        psm[r][c] = path[(size_t)(m0 + r) * 16 + lbase + c];
    }

    const int colb = (((lane & 7) ^ (lane >> 3)) << 4);
    const int rl = lane >> 3;

    f32x4 accF[4][4], accL[4][4];
#pragma unroll
    for (int a = 0; a < 4; ++a)
#pragma unroll
        for (int b = 0; b < 4; ++b) {
            accF[a][b] = (f32x4){0.f, 0.f, 0.f, 0.f};
            accL[a][b] = (f32x4){0.f, 0.f, 0.f, 0.f};
        }

    const int nsteps = LPB << 4;
    for (int sl = 0; sl < nsteps; ++sl) {
        const int l_ = lbase + (sl >> 4);
        const int h2_ = (sl & 15) << 7;
#pragma unroll
        for (int i_ = 0; i_ < 4; ++i_) {
            int seg_ = wid * 4 + i_;
            int r_ = seg_ * 8 + rl;
            lds16((const char*)xb + (size_t)(m0 + r_) * 2048 + h2_ + colb,
                  (char*)Asm + seg_ * 1024);
            lds16((const char*)wlt + (size_t)(l_ * 1024 + n0 + r_) * 2048 + h2_ + colb,
                  (char*)Bsm + seg_ * 1024);
        }
        __syncthreads();

#pragma unroll
        for (int kf = 0; kf < 2; ++kf) {
            int c2 = kf * 64 + ((lane >> 4) << 4);
            bf16x8 af[4], bfr[4];
#pragma unroll
            for (int mf = 0; mf < 4; ++mf) {
                int rr = wm * 64 + mf * 16 + (lane & 15);
                af[mf] = *(const bf16x8*)((const char*)Asm + rr * 128 + (c2 ^ ((lane & 7) << 4)));
            }
#pragma unroll
            for (int nf = 0; nf < 4; ++nf) {
                int rr = wn * 64 + nf * 16 + (lane & 15);
                bfr[nf] = *(const bf16x8*)((const char*)Bsm + rr * 128 + (c2 ^ ((lane & 7) << 4)));
            }
#pragma unroll
            for (int mf = 0; mf < 4; ++mf)
#pragma unroll
                for (int nf = 0; nf < 4; ++nf)
                    accL[mf][nf] = __builtin_amdgcn_mfma_f32_16x16x32_bf16(
                        af[mf], bfr[nf], accL[mf][nf], 0, 0, 0);
        }
        __syncthreads();

        if ((sl & 15) == 15) {
            int ll = sl >> 4;
#pragma unroll
            for (int mf = 0; mf < 4; ++mf)
#pragma unroll
                for (int jj = 0; jj < 4; ++jj) {
                    float p = psm[wm * 64 + mf * 16 + ((lane >> 4) << 2) + jj][ll];
#pragma unroll
                    for (int nf = 0; nf < 4; ++nf) {
                        accF[mf][nf][jj] += p * accL[mf][nf][jj];
                        accL[mf][nf][jj] = 0.f;
                    }
                }
        }
    }

    float* po = pout + (size_t)blockIdx.z * M * 1024;
#pragma unroll
    for (int mf = 0; mf < 4; ++mf)
#pragma unroll
        for (int jj = 0; jj < 4; ++jj) {
            int rowl = wm * 64 + mf * 16 + ((lane >> 4) << 2) + jj;
#pragma unroll
            for (int nf = 0; nf < 4; ++nf) {
                int col = n0 + wn * 64 + nf * 16 + (lane & 15);
                po[(size_t)(m0 + rowl) * 1024 + col] = accF[mf][nf][jj];
            }
        }
}

// ---------------- R: out = [readOut? out] + sum_g extra[g] + path @ bl -----
// extra is f16 (ext16=1) or f32 (ext16=0) partials.
__global__ __launch_bounds__(256) void reduce_kernel(
    const void* __restrict__ extra, const float* __restrict__ path,
    const float* __restrict__ bl, float* __restrict__ out, int M,
    int nExtra, int readOut, int ext16) {
    int m = blockIdx.x, t = threadIdx.x;
    size_t i4 = (size_t)m * 256 + t;
    f32x4 acc = {0.f, 0.f, 0.f, 0.f};
    if (readOut) acc = ((const f32x4*)out)[i4];
    if (ext16) {
        const ushort4* e = (const ushort4*)extra;
        for (int g = 0; g < nExtra; ++g) {
            ushort4 v = e[(size_t)g * M * 256 + i4];
            acc[0] += h2f(v.x);
            acc[1] += h2f(v.y);
            acc[2] += h2f(v.z);
            acc[3] += h2f(v.w);
        }
    } else {
        const f32x4* e = (const f32x4*)extra;
        for (int g = 0; g < nExtra; ++g) acc += e[(size_t)g * M * 256 + i4];
    }
#pragma unroll
    for (int l = 0; l < 16; ++l) {
        float p = path[(size_t)m * 16 + l];
        f32x4 b = ((const f32x4*)bl)[l * 256 + t];
        acc += p * b;
    }
    ((f32x4*)out)[i4] = acc;
}

extern "C" void kernel_launch(void* const* d_in, const int* in_sizes, int n_in,
                              void* d_out, int out_size, void* d_ws, size_t ws_size,
                              hipStream_t stream) {
    const float* x  = (const float*)d_in[0];   // (B,S,H)
    const float* Wd = (const float*)d_in[1];   // (15,H,2)
    const float* bd = (const float*)d_in[2];   // (15,2)
    const float* Wl = (const float*)d_in[3];   // (16,H,H)
    const float* bl = (const float*)d_in[4];   // (16,H)
    float* out = (float*)d_out;

    const int H = 1024;
    const int M = in_sizes[0] / H;  // B*S = 4096
    char* ws = (char*)d_ws;

    // main-path ws layout: path | xh (M*1024 f16) | wlt f16 | 3 f16 partials (~64.3 MB)
    size_t n_off_xh   = (size_t)M * 16 * 4;
    size_t n_off_wlt  = n_off_xh + (size_t)M * 1024 * 2;
    size_t n_off_part = n_off_wlt + (size_t)16 * 1024 * 1024 * 2;
    size_t n_need     = n_off_part + 3 * (size_t)M * 1024 * 2;

    if (ws_size >= n_need && (M % 256) == 0) {
        float* path = (float*)ws;
        u16* xh  = (u16*)(ws + n_off_xh);
        u16* wlt = (u16*)(ws + n_off_wlt);
        u16* part16 = (u16*)(ws + n_off_part);

        pre_kernel<<<4096 + M / 4, 256, 0, stream>>>(x, Wd, bd, Wl, path, xh, wlt, 1, M);
        tree_gemm8<<<4 * (M / 256) * 4, 1024, 0, stream>>>(xh, wlt, path, out, part16, M);
        reduce_kernel<<<M, 256, 0, stream>>>(part16, path, bl, out, M, 3, 1, 1);
        return;
    }

    // fallback: round-2 pipeline (bf16, f32 partials)
    size_t off_xb   = (size_t)M * 16 * 4;
    size_t off_wlt  = off_xb + (size_t)M * 1024 * 2;
    size_t off_part = off_wlt + (size_t)16 * 1024 * 1024 * 2;
    size_t per_part = (size_t)M * 1024 * 4;

    int G = 1;
    if (ws_size >= off_part + 4 * per_part) G = 4;
    else if (ws_size >= off_part + 2 * per_part) G = 2;
    const int LPB = 16 / G;
    const int lgLPB = (G == 1) ? 4 : (G == 2) ? 3 : 2;

    float* path = (float*)ws;
    u16* xb  = (u16*)(ws + off_xb);
    u16* wlt = (u16*)(ws + off_wlt);
    float* pout = (G == 1) ? out : (float*)(ws + off_part);

    pre_kernel<<<4096 + (M + 3) / 4, 256, 0, stream>>>(x, Wd, bd, Wl, path, xb, wlt, 0, M);
    tree_gemm_fb<<<dim3(8, M / 128, G), 256, 0, stream>>>(xb, wlt, path, pout, M, LPB, lgLPB);
    reduce_kernel<<<M, 256, 0, stream>>>(pout, path, bl, out, M,
                                         (G == 1) ? 0 : G, (G == 1) ? 1 : 0, 0);
}

// Round 16
// 194.820 us; speedup vs baseline: 1.1040x; 1.1040x over previous
//
#include <hip/hip_runtime.h>
#include <hip/hip_bf16.h>

typedef unsigned short u16;
typedef unsigned int u32;
typedef short bf16x8 __attribute__((ext_vector_type(8)));
typedef _Float16 f16x8 __attribute__((ext_vector_type(8)));
typedef float f32x4 __attribute__((ext_vector_type(4)));

__device__ __forceinline__ u16 f2bf(float f) {
    u32 u = __builtin_bit_cast(u32, f);
    u32 r = (u + 0x7FFFu + ((u >> 16) & 1u)) >> 16;
    return (u16)r;
}
__device__ __forceinline__ u16 f2h(float f) {
    _Float16 h = (_Float16)f;
    return __builtin_bit_cast(u16, h);
}
__device__ __forceinline__ float h2f(u16 u) {
    return (float)__builtin_bit_cast(_Float16, u);
}

// async global->LDS, 16B per lane (lds dest = wave-uniform base + lane*16)
__device__ __forceinline__ void lds16(const void* g, void* s) {
    __builtin_amdgcn_global_load_lds(
        (const __attribute__((address_space(1))) u32*)g,
        (__attribute__((address_space(3))) u32*)s, 16, 0, 0);
}

// ---------------- P1: decisions -> path; x -> half (f16) or bf16 ----------------
__global__ __launch_bounds__(256) void path_kernel(
    const float* __restrict__ x, const float* __restrict__ Wd,
    const float* __restrict__ bd, float* __restrict__ path,
    u16* __restrict__ xb, int as_f16, int M) {
    int lane = threadIdx.x & 63;
    int wid = threadIdx.x >> 6;
    int m = blockIdx.x * 4 + wid;
    if (m >= M) return;

    const float* xr = x + (size_t)m * 1024;
    float v[16];
#pragma unroll
    for (int i = 0; i < 16; ++i) v[i] = xr[lane + 64 * i];
#pragma unroll
    for (int i = 0; i < 16; ++i)
        xb[(size_t)m * 1024 + lane + 64 * i] = as_f16 ? f2h(v[i]) : f2bf(v[i]);

    int leaf = lane & 15;
    int nd[4], bit[4];
#pragma unroll
    for (int k = 0; k < 4; ++k) {
        nd[k] = (1 << k) - 1 + (leaf & ((1 << k) - 1));
        bit[k] = (leaf >> k) & 1;
    }
    float z[4] = {0.f, 0.f, 0.f, 0.f};

    const float2* Wd2 = (const float2*)Wd;  // [n][h] -> (k0,k1)
    for (int n = 0; n < 15; ++n) {
        float s0 = 0.f, s1 = 0.f;
#pragma unroll
        for (int i = 0; i < 16; ++i) {
            float2 w = Wd2[n * 1024 + lane + 64 * i];
            s0 += v[i] * w.x;
            s1 += v[i] * w.y;
        }
#pragma unroll
        for (int off = 32; off; off >>= 1) {
            s0 += __shfl_xor(s0, off, 64);
            s1 += __shfl_xor(s1, off, 64);
        }
#pragma unroll
        for (int k = 0; k < 4; ++k)
            if (nd[k] == n) z[k] = bit[k] ? s1 : s0;
    }
    float p = 1.f;
#pragma unroll
    for (int k = 0; k < 4; ++k) {
        float zz = z[k] + bd[nd[k] * 2 + bit[k]];
        p *= 1.f / (1.f + expf(-zz));
    }
    if (lane < 16) path[(size_t)m * 16 + leaf] = p;
}

// ---------------- P2: Wl (l,h,n) fp32 -> WlT (l,n,h) f16/bf16 ----------------
__global__ __launch_bounds__(256) void wlt_kernel(
    const float* __restrict__ Wl, u16* __restrict__ wlt, int as_f16) {
    __shared__ float tile[64][65];
    int l = blockIdx.z, hb = blockIdx.y, nb = blockIdx.x;
    int t = threadIdx.x;
    int r = t >> 2, cq = (t & 3) << 4;

    const float* src = Wl + ((size_t)(l * 1024 + hb * 64 + r)) * 1024 + nb * 64 + cq;
#pragma unroll
    for (int j = 0; j < 4; ++j) {
        float4 w = ((const float4*)src)[j];
        tile[r][cq + 4 * j + 0] = w.x;
        tile[r][cq + 4 * j + 1] = w.y;
        tile[r][cq + 4 * j + 2] = w.z;
        tile[r][cq + 4 * j + 3] = w.w;
    }
    __syncthreads();
    union { u16 u[16]; uint4 q[2]; } pk;
#pragma unroll
    for (int j = 0; j < 16; ++j)
        pk.u[j] = as_f16 ? f2h(tile[cq + j][r]) : f2bf(tile[cq + j][r]);
    u16* dst = wlt + ((size_t)(l * 1024 + nb * 64 + r)) * 1024 + hb * 64 + cq;
    ((uint4*)dst)[0] = pk.q[0];
    ((uint4*)dst)[1] = pk.q[1];
}

// ---------------- G8: 256x256, ks-major, A staged once per ks (reused 4 leaves),
// 16x16x32 f16 MFMA, 8 waves (128x64 wave tiles), ONE barrier per leaf-tile,
// compiler-scheduled lgkm, r11 vmcnt ledger. Proven 148-150us / 40% MfmaUtil. -------
__global__ __launch_bounds__(512, 2) void tree_gemm8(
    const u16* __restrict__ xh, const u16* __restrict__ wlt,
    const float* __restrict__ path, float* __restrict__ out,
    u16* __restrict__ part16, int M) {
    __shared__ __align__(16) u16 Asm[2][2][128 * 64];  // [ks-parity][m-half]
    __shared__ __align__(16) u16 Bsm[2][2][128 * 64];  // [t-parity][n-half]
    __shared__ u16 psm_h[4][256];                      // f16 path [leaf][row]

    const int tid = threadIdx.x, lane = tid & 63, w = tid >> 6;
    const int wm = w >> 2, wn = w & 3;
    // XCD quad-swizzle: 4 n0-blocks sharing an A panel + same z -> one XCD
    const int nbm = M >> 8;
    int xb_, yb_, zb_;
    {
        int bid = blockIdx.x;
        if ((nbm << 4) == 256) {
            int k = bid & 7, s = bid >> 3;
            zb_ = k >> 1; yb_ = (k & 1) * 8 + (s >> 2); xb_ = s & 3;
        } else {
            xb_ = bid & 3; int t2 = bid >> 2; yb_ = t2 % nbm; zb_ = t2 / nbm;
        }
    }
    const int n0 = xb_ * 256, m0 = yb_ * 256, z = zb_;
    const int z4 = z * 4;
    const int rl = lane >> 3;                      // dest row & 7 within 8-row seg
    const int srcswz = ((lane & 7) ^ rl) << 4;     // pre-swizzled source col
    const int arow = (lane & 15) * 128;            // frag-row byte (16-row frags)
    const int coff0 = ((lane >> 4) << 4) ^ ((lane & 7) << 4);

    // stage f16 path columns for this z-group: psm_h[lz][row]
    for (int i = tid; i < 1024; i += 512) {
        int r = i >> 2, lz = i & 3;
        psm_h[lz][r] = f2h(path[(size_t)(m0 + r) * 16 + z4 + lz]);
    }

#define ISSUE_A(dst_, ks_)                                                          \
    {                                                                               \
        _Pragma("unroll") for (int h_ = 0; h_ < 2; ++h_)                            \
        _Pragma("unroll") for (int j_ = 0; j_ < 2; ++j_)                            \
            lds16((const char*)xh +                                                 \
                      (size_t)(m0 + h_ * 128 + w * 16 + j_ * 8 + rl) * 2048 +       \
                      ((ks_) << 7) + srcswz,                                        \
                  (dst_) + h_ * 16384 + w * 2048 + j_ * 1024);                      \
    }
#define ISSUE_B(dst_, t_)                                                           \
    if ((t_) < 64) {                                                                \
        size_t lb_ = (size_t)(z4 + ((t_) & 3)) * 2097152 +                          \
                     ((size_t)((t_) >> 2) << 7);                                    \
        _Pragma("unroll") for (int h_ = 0; h_ < 2; ++h_)                            \
        _Pragma("unroll") for (int j_ = 0; j_ < 2; ++j_)                            \
            lds16((const char*)wlt + lb_ +                                          \
                      (size_t)(n0 + h_ * 128 + w * 16 + j_ * 8 + rl) * 2048 +       \
                      srcswz,                                                       \
                  (dst_) + h_ * 16384 + w * 2048 + j_ * 1024);                      \
    }
#define LDA4(aB_, mfb)                                                              \
    _Pragma("unroll") for (int q_ = 0; q_ < 4; ++q_) {                              \
        aR[q_][0] = *(const f16x8*)((aB_) + ((mfb) + q_) * 2048 + coff0);           \
        aR[q_][1] = *(const f16x8*)((aB_) + ((mfb) + q_) * 2048 + (coff0 ^ 64));    \
    }
#define LDB2(bB_, nfb, d0)                                                          \
    _Pragma("unroll") for (int q_ = 0; q_ < 2; ++q_) {                              \
        bR[(d0) + q_][0] = *(const f16x8*)((bB_) + ((nfb) + q_) * 2048 + coff0);    \
        bR[(d0) + q_][1] =                                                          \
            *(const f16x8*)((bB_) + ((nfb) + q_) * 2048 + (coff0 ^ 64));            \
    }
#define LDP(ll, mfb)                                                                \
    _Pragma("unroll") for (int q_ = 0; q_ < 4; ++q_)                                \
        p2[q_] = __builtin_bit_cast(                                                \
            _Float16, psm_h[ll][wm * 128 + ((mfb) + q_) * 16 + (lane & 15)]);
#define SCALE                                                                       \
    _Pragma("unroll") for (int q_ = 0; q_ < 4; ++q_) {                              \
        aR[q_][0] *= p2[q_];                                                        \
        aR[q_][1] *= p2[q_];                                                        \
    }
#define MM(a0, b0)                                                                  \
    _Pragma("unroll") for (int mq_ = 0; mq_ < 4; ++mq_)                             \
    _Pragma("unroll") for (int nq_ = 0; nq_ < 2; ++nq_) {                           \
        acc[(a0) + mq_][(b0) + nq_] = __builtin_amdgcn_mfma_f32_16x16x32_f16(       \
            aR[mq_][0], bR[(b0) + nq_][0], acc[(a0) + mq_][(b0) + nq_], 0, 0, 0);   \
        acc[(a0) + mq_][(b0) + nq_] = __builtin_amdgcn_mfma_f32_16x16x32_f16(       \
            aR[mq_][1], bR[(b0) + nq_][1], acc[(a0) + mq_][(b0) + nq_], 0, 0, 0);   \
    }
#define BAR __builtin_amdgcn_s_barrier()
#define SCHED0 __builtin_amdgcn_sched_barrier(0)
#define PRIO1 __builtin_amdgcn_s_setprio(1)
#define PRIO0 __builtin_amdgcn_s_setprio(0)
#define VM0 asm volatile("s_waitcnt vmcnt(0)" ::: "memory")
#define VM4 asm volatile("s_waitcnt vmcnt(4)" ::: "memory")
#define NOPX ((void)0)

// one leaf-tile, ONE barrier (at end). No manual lgkm drains: compiler tracks
// ds_read->MFMA register deps and emits counted lgkmcnt interleaves.
#define TILE(aB_, bB_, ll, EB, EA, WT)                                              \
    {                                                                               \
        f16x8 aR[4][2], bR[4][2];                                                   \
        _Float16 p2[4];                                                             \
        LDA4(aB_, 0); LDB2(bB_, 0, 0); LDB2(bB_, 2, 2); LDP(ll, 0);                 \
        EB; EA;                                                                     \
        SCALE;                                                                      \
        PRIO1; MM(0, 0); MM(0, 2); PRIO0;                                           \
        LDA4(aB_, 4); LDP(ll, 4);                                                   \
        SCALE;                                                                      \
        PRIO1; MM(4, 0); MM(4, 2); PRIO0;                                           \
        WT; BAR;                                                                    \
    }

    f32x4 acc[8][4];
#pragma unroll
    for (int a = 0; a < 8; ++a)
#pragma unroll
        for (int b = 0; b < 4; ++b) acc[a][b] = (f32x4){0.f, 0.f, 0.f, 0.f};

    const char* aBase0 = (const char*)Asm[0][wm] + arow;
    const char* aBase1 = (const char*)Asm[1][wm] + arow;
    const char* bBase0 = (const char*)Bsm[0][wn >> 1] + (wn & 1) * 8192 + arow;
    const char* bBase1 = (const char*)Bsm[1][wn >> 1] + (wn & 1) * 8192 + arow;
    char* aSlot0 = (char*)Asm[0][0];
    char* aSlot1 = (char*)Asm[1][0];
    char* bSlot0 = (char*)Bsm[0][0];
    char* bSlot1 = (char*)Bsm[1][0];

    // prologue: A(ks0) + B(0); drain fully (incl. psm ds_writes); sync
    ISSUE_A(aSlot0, 0);
    ISSUE_B(bSlot0, 0);
    asm volatile("s_waitcnt vmcnt(0) lgkmcnt(0)" ::: "memory");
    BAR;
    SCHED0;

    // ledger per tile (4-load units), issues in order B then A:
    // ll0: issue B(t+1) -> [B4]             -> VM0 (B had full-tile flight)
    // ll1: issue B(t+2), A(ks+1) -> [B4,A4] -> VM4 (drain B, keep A flying)
    // ll2: entry [A4], issue B -> [A4,B4]   -> VM0
    // ll3: issue B -> [B4]                  -> VM0
#pragma unroll 1
    for (int ks = 0; ks < 15; ++ks) {
        const int t4 = ks << 2;
        const char* aB = (ks & 1) ? aBase1 : aBase0;
        char* aD = (ks & 1) ? aSlot0 : aSlot1;  // slot for A(ks+1)
        TILE(aB, bBase0, 0, ISSUE_B(bSlot1, t4 + 1), NOPX, VM0);
        TILE(aB, bBase1, 1, ISSUE_B(bSlot0, t4 + 2), ISSUE_A(aD, ks + 1), VM4);
        TILE(aB, bBase0, 2, ISSUE_B(bSlot1, t4 + 3), NOPX, VM0);
        TILE(aB, bBase1, 3, ISSUE_B(bSlot0, t4 + 4), NOPX, VM0);
    }
    {   // ks = 15 tail: no A prefetch; B issues run out at t=63
        const char* aB = aBase1;
        TILE(aB, bBase0, 0, ISSUE_B(bSlot1, 61), NOPX, VM0);
        TILE(aB, bBase1, 1, ISSUE_B(bSlot0, 62), NOPX, VM0);
        TILE(aB, bBase0, 2, ISSUE_B(bSlot1, 63), NOPX, VM0);
        TILE(aB, bBase1, 3, NOPX, NOPX, NOPX);
    }

    // epilogue: z=0 -> f32 to out; z>0 -> f16 partial (z-1)
    const int r0 = m0 + wm * 128 + ((lane >> 4) << 2);
    const int c0 = n0 + wn * 64 + (lane & 15);
    if (z == 0) {
#pragma unroll
        for (int mf = 0; mf < 8; ++mf)
#pragma unroll
            for (int jj = 0; jj < 4; ++jj)
#pragma unroll
                for (int nf = 0; nf < 4; ++nf)
                    out[(size_t)(r0 + mf * 16 + jj) * 1024 + c0 + nf * 16] =
                        acc[mf][nf][jj];
    } else {
        u16* po = part16 + (size_t)(z - 1) * M * 1024;
#pragma unroll
        for (int mf = 0; mf < 8; ++mf)
#pragma unroll
            for (int jj = 0; jj < 4; ++jj)
#pragma unroll
                for (int nf = 0; nf < 4; ++nf)
                    po[(size_t)(r0 + mf * 16 + jj) * 1024 + c0 + nf * 16] =
                        f2h(acc[mf][nf][jj]);
    }
#undef ISSUE_A
#undef ISSUE_B
#undef LDA4
#undef LDB2
#undef LDP
#undef SCALE
#undef MM
#undef BAR
#undef SCHED0
#undef PRIO1
#undef PRIO0
#undef VM0
#undef VM4
#undef NOPX
#undef TILE
}

// ---------------- FB: round-2 dual-accumulator bf16 GEMM (fallback) -------
__global__ __launch_bounds__(256) void tree_gemm_fb(
    const u16* __restrict__ xb, const u16* __restrict__ wlt,
    const float* __restrict__ path, float* __restrict__ pout,
    int M, int LPB, int lgLPB) {
    __shared__ __align__(16) u16 Asm[128 * 64];
    __shared__ __align__(16) u16 Bsm[128 * 64];
    __shared__ float psm[128][16];

    const int tid = threadIdx.x, lane = tid & 63, wid = tid >> 6;
    const int wm = wid >> 1, wn = wid & 1;
    const int m0 = blockIdx.y * 128, n0 = blockIdx.x * 128;
    const int lbase = blockIdx.z * LPB;

    for (int i = tid; i < (128 << lgLPB); i += 256) {
        int r = i >> lgLPB, c = i & (LPB - 1);
        psm[r][c] = path[(size_t)(m0 + r) * 16 + lbase + c];
    }

    const int colb = (((lane & 7) ^ (lane >> 3)) << 4);
    const int rl = lane >> 3;

    f32x4 accF[4][4], accL[4][4];
#pragma unroll
    for (int a = 0; a < 4; ++a)
#pragma unroll
        for (int b = 0; b < 4; ++b) {
            accF[a][b] = (f32x4){0.f, 0.f, 0.f, 0.f};
            accL[a][b] = (f32x4){0.f, 0.f, 0.f, 0.f};
        }

    const int nsteps = LPB << 4;
    for (int sl = 0; sl < nsteps; ++sl) {
        const int l_ = lbase + (sl >> 4);
        const int h2_ = (sl & 15) << 7;
#pragma unroll
        for (int i_ = 0; i_ < 4; ++i_) {
            int seg_ = wid * 4 + i_;
            int r_ = seg_ * 8 + rl;
            lds16((const char*)xb + (size_t)(m0 + r_) * 2048 + h2_ + colb,
                  (char*)Asm + seg_ * 1024);
            lds16((const char*)wlt + (size_t)(l_ * 1024 + n0 + r_) * 2048 + h2_ + colb,
                  (char*)Bsm + seg_ * 1024);
        }
        __syncthreads();

#pragma unroll
        for (int kf = 0; kf < 2; ++kf) {
            int c2 = kf * 64 + ((lane >> 4) << 4);
            bf16x8 af[4], bfr[4];
#pragma unroll
            for (int mf = 0; mf < 4; ++mf) {
                int rr = wm * 64 + mf * 16 + (lane & 15);
                af[mf] = *(const bf16x8*)((const char*)Asm + rr * 128 + (c2 ^ ((lane & 7) << 4)));
            }
#pragma unroll
            for (int nf = 0; nf < 4; ++nf) {
                int rr = wn * 64 + nf * 16 + (lane & 15);
                bfr[nf] = *(const bf16x8*)((const char*)Bsm + rr * 128 + (c2 ^ ((lane & 7) << 4)));
            }
#pragma unroll
            for (int mf = 0; mf < 4; ++mf)
#pragma unroll
                for (int nf = 0; nf < 4; ++nf)
                    accL[mf][nf] = __builtin_amdgcn_mfma_f32_16x16x32_bf16(
                        af[mf], bfr[nf], accL[mf][nf], 0, 0, 0);
        }
        __syncthreads();

        if ((sl & 15) == 15) {
            int ll = sl >> 4;
#pragma unroll
            for (int mf = 0; mf < 4; ++mf)
#pragma unroll
                for (int jj = 0; jj < 4; ++jj) {
                    float p = psm[wm * 64 + mf * 16 + ((lane >> 4) << 2) + jj][ll];
#pragma unroll
                    for (int nf = 0; nf < 4; ++nf) {
                        accF[mf][nf][jj] += p * accL[mf][nf][jj];
                        accL[mf][nf][jj] = 0.f;
                    }
                }
        }
    }

    float* po = pout + (size_t)blockIdx.z * M * 1024;
#pragma unroll
    for (int mf = 0; mf < 4; ++mf)
#pragma unroll
        for (int jj = 0; jj < 4; ++jj) {
            int rowl = wm * 64 + mf * 16 + ((lane >> 4) << 2) + jj;
#pragma unroll
            for (int nf = 0; nf < 4; ++nf) {
                int col = n0 + wn * 64 + nf * 16 + (lane & 15);
                po[(size_t)(m0 + rowl) * 1024 + col] = accF[mf][nf][jj];
            }
        }
}

// ---------------- R: out = [readOut? out] + sum_g extra[g] + path @ bl -----
// extra is f16 (ext16=1) or f32 (ext16=0) partials.
__global__ __launch_bounds__(256) void reduce_kernel(
    const void* __restrict__ extra, const float* __restrict__ path,
    const float* __restrict__ bl, float* __restrict__ out, int M,
    int nExtra, int readOut, int ext16) {
    int m = blockIdx.x, t = threadIdx.x;
    size_t i4 = (size_t)m * 256 + t;
    f32x4 acc = {0.f, 0.f, 0.f, 0.f};
    if (readOut) acc = ((const f32x4*)out)[i4];
    if (ext16) {
        const ushort4* e = (const ushort4*)extra;
        for (int g = 0; g < nExtra; ++g) {
            ushort4 v = e[(size_t)g * M * 256 + i4];
            acc[0] += h2f(v.x);
            acc[1] += h2f(v.y);
            acc[2] += h2f(v.z);
            acc[3] += h2f(v.w);
        }
    } else {
        const f32x4* e = (const f32x4*)extra;
        for (int g = 0; g < nExtra; ++g) acc += e[(size_t)g * M * 256 + i4];
    }
#pragma unroll
    for (int l = 0; l < 16; ++l) {
        float p = path[(size_t)m * 16 + l];
        f32x4 b = ((const f32x4*)bl)[l * 256 + t];
        acc += p * b;
    }
    ((f32x4*)out)[i4] = acc;
}

extern "C" void kernel_launch(void* const* d_in, const int* in_sizes, int n_in,
                              void* d_out, int out_size, void* d_ws, size_t ws_size,
                              hipStream_t stream) {
    const float* x  = (const float*)d_in[0];   // (B,S,H)
    const float* Wd = (const float*)d_in[1];   // (15,H,2)
    const float* bd = (const float*)d_in[2];   // (15,2)
    const float* Wl = (const float*)d_in[3];   // (16,H,H)
    const float* bl = (const float*)d_in[4];   // (16,H)
    float* out = (float*)d_out;

    const int H = 1024;
    const int M = in_sizes[0] / H;  // B*S = 4096
    char* ws = (char*)d_ws;

    // main-path ws layout: path | xh (M*1024 f16) | wlt f16 | 3 f16 partials (~64.3 MB)
    size_t n_off_xh   = (size_t)M * 16 * 4;
    size_t n_off_wlt  = n_off_xh + (size_t)M * 1024 * 2;
    size_t n_off_part = n_off_wlt + (size_t)16 * 1024 * 1024 * 2;
    size_t n_need     = n_off_part + 3 * (size_t)M * 1024 * 2;

    if (ws_size >= n_need && (M % 256) == 0) {
        float* path = (float*)ws;
        u16* xh  = (u16*)(ws + n_off_xh);
        u16* wlt = (u16*)(ws + n_off_wlt);
        u16* part16 = (u16*)(ws + n_off_part);

        path_kernel<<<M / 4, 256, 0, stream>>>(x, Wd, bd, path, xh, 1, M);
        wlt_kernel<<<dim3(16, 16, 16), 256, 0, stream>>>(Wl, wlt, 1);
        tree_gemm8<<<4 * (M / 256) * 4, 512, 0, stream>>>(xh, wlt, path, out, part16, M);
        reduce_kernel<<<M, 256, 0, stream>>>(part16, path, bl, out, M, 3, 1, 1);
        return;
    }

    // fallback: round-2 pipeline (bf16, f32 partials)
    size_t off_xb   = (size_t)M * 16 * 4;
    size_t off_wlt  = off_xb + (size_t)M * 1024 * 2;
    size_t off_part = off_wlt + (size_t)16 * 1024 * 1024 * 2;
    size_t per_part = (size_t)M * 1024 * 4;

    int G = 1;
    if (ws_size >= off_part + 4 * per_part) G = 4;
    else if (ws_size >= off_part + 2 * per_part) G = 2;
    const int LPB = 16 / G;
    const int lgLPB = (G == 1) ? 4 : (G == 2) ? 3 : 2;

    float* path = (float*)ws;
    u16* xb  = (u16*)(ws + off_xb);
    u16* wlt = (u16*)(ws + off_wlt);
    float* pout = (G == 1) ? out : (float*)(ws + off_part);

    path_kernel<<<M / 4, 256, 0, stream>>>(x, Wd, bd, path, xb, 0, M);
    wlt_kernel<<<dim3(16, 16, 16), 256, 0, stream>>>(Wl, wlt, 0);
    tree_gemm_fb<<<dim3(8, M / 128, G), 256, 0, stream>>>(xb, wlt, path, pout, M, LPB, lgLPB);
    reduce_kernel<<<M, 256, 0, stream>>>(pout, path, bl, out, M,
                                         (G == 1) ? 0 : G, (G == 1) ? 1 : 0, 0);
}